// Round 1
// baseline (1136.883 us; speedup 1.0000x reference)
//
#include <hip/hip_runtime.h>
#include <math.h>

#define B_    2
#define L_    2048
#define H_    16
#define D_    128
#define S_    40
#define NTOP_ 40

__constant__ const float SCALE_ = 0.08838834764831843f; // 1/sqrt(128)

// ---------------- Kernel A: sampled sparsity measure M[b,h,q] ----------------
// One wave (64 lanes) per query row. Lane holds 2 consecutive floats of Q row.
__global__ __launch_bounds__(256) void k_sampleM(const float* __restrict__ Q,
                                                 const float* __restrict__ K,
                                                 const int* __restrict__ idx,
                                                 float* __restrict__ M) {
    const int wave = threadIdx.x >> 6;
    const int lane = threadIdx.x & 63;
    const int gid  = blockIdx.x * 4 + wave;      // (b*H + h)*L + q
    const int q  = gid & (L_ - 1);
    const int hb = gid >> 11;                    // b*H + h
    const int h  = hb & (H_ - 1);
    const int b  = hb >> 4;

    const float2* qrow = (const float2*)(Q + (((size_t)(b * L_ + q)) * H_ + h) * D_);
    const float2 qv = qrow[lane];

    const int* ip = idx + q * S_;
    float maxv = -INFINITY, sumv = 0.0f;
    for (int s = 0; s < S_; ++s) {
        const int ki = ip[s];
        const float2* krow = (const float2*)(K + (((size_t)(b * L_ + ki)) * H_ + h) * D_);
        const float2 kv = krow[lane];
        float p = qv.x * kv.x + qv.y * kv.y;
        #pragma unroll
        for (int o = 32; o; o >>= 1) p += __shfl_xor(p, o, 64);
        maxv = fmaxf(maxv, p);
        sumv += p;
    }
    if (lane == 0) M[gid] = maxv - sumv * (1.0f / L_);
}

// ---------------- Kernel B: top-40 indices per (b,h) ----------------
// Iterative argmax, ties -> smallest index (matches jax.lax.top_k set).
__global__ __launch_bounds__(256) void k_topk(const float* __restrict__ M,
                                              int* __restrict__ topk) {
    __shared__ float m[L_];
    __shared__ float bv[256];
    __shared__ int   bi[256];
    const int bh = blockIdx.x;
    const int t  = threadIdx.x;
    const float* Mrow = M + (size_t)bh * L_;
    for (int i = t; i < L_; i += 256) m[i] = Mrow[i];
    __syncthreads();
    for (int it = 0; it < NTOP_; ++it) {
        float best = -INFINITY; int besti = 0;
        for (int i = t; i < L_; i += 256) {
            float v = m[i];
            if (v > best) { best = v; besti = i; }
        }
        bv[t] = best; bi[t] = besti;
        __syncthreads();
        for (int s = 128; s; s >>= 1) {
            if (t < s) {
                float ov = bv[t + s]; int oi = bi[t + s];
                if (ov > bv[t] || (ov == bv[t] && oi < bi[t])) { bv[t] = ov; bi[t] = oi; }
            }
            __syncthreads();
        }
        if (t == 0) {
            topk[bh * NTOP_ + it] = bi[0];
            m[bi[0]] = -INFINITY;
        }
        __syncthreads();
    }
}

// ---------------- Kernel C: V mean over L per (b,h,d) ----------------
__global__ __launch_bounds__(256) void k_vmean(const float* __restrict__ V,
                                               float* __restrict__ vmean) {
    __shared__ float sdata[256];
    const int bh = blockIdx.x;
    const int h  = bh & (H_ - 1);
    const int b  = bh >> 4;
    const int t  = threadIdx.x;
    const int d  = t & (D_ - 1);
    const int lp = t >> 7;  // 0 or 1
    float acc = 0.0f;
    for (int l = lp; l < L_; l += 2)
        acc += V[(((size_t)(b * L_ + l)) * H_ + h) * D_ + d];
    sdata[t] = acc;
    __syncthreads();
    if (t < D_) vmean[bh * D_ + t] = (sdata[t] + sdata[t + 128]) * (1.0f / L_);
}

// ---------------- Kernel D: broadcast-fill output with V mean ----------------
// out[b,l,h,d] = vmean[b,h,d]; float4 grid-stride.
__global__ __launch_bounds__(256) void k_fill(float4* __restrict__ out,
                                              const float4* __restrict__ vmean4) {
    const size_t total = (size_t)B_ * L_ * H_ * D_ / 4;   // 2097152
    for (size_t i = blockIdx.x * 256 + threadIdx.x; i < total; i += (size_t)gridDim.x * 256) {
        const size_t flat = i * 4;
        const int d = (int)(flat & (D_ - 1));
        const int h = (int)((flat >> 7) & (H_ - 1));
        const int b = (int)(flat >> 22);                  // / (L_*H_*D_)
        out[i] = vmean4[(((b << 4) + h) * D_ + d) >> 2];
    }
}

// ---------------- Kernel E: full attention for the selected rows ----------------
// One block per (b,h,u). Scores + softmax in LDS, then dense PV.
__global__ __launch_bounds__(256) void k_attn(const float* __restrict__ Q,
                                              const float* __restrict__ K,
                                              const float* __restrict__ V,
                                              const int* __restrict__ topk,
                                              float* __restrict__ out) {
    __shared__ float qs[D_];
    __shared__ float attn[L_];
    __shared__ float red[256];
    const int blk = blockIdx.x;
    const int u   = blk % NTOP_;
    const int bh  = blk / NTOP_;
    const int h   = bh & (H_ - 1);
    const int b   = bh >> 4;
    const int t   = threadIdx.x;
    const int qi  = topk[bh * NTOP_ + u];

    if (t < D_) qs[t] = Q[(((size_t)(b * L_ + qi)) * H_ + h) * D_ + t];
    __syncthreads();

    // scores
    float lmax = -INFINITY;
    for (int kk = t; kk < L_; kk += 256) {
        const float4* kr = (const float4*)(K + (((size_t)(b * L_ + kk)) * H_ + h) * D_);
        float acc = 0.0f;
        #pragma unroll
        for (int j = 0; j < D_ / 4; ++j) {
            const float4 kv = kr[j];
            acc += kv.x * qs[4*j] + kv.y * qs[4*j+1] + kv.z * qs[4*j+2] + kv.w * qs[4*j+3];
        }
        acc *= SCALE_;
        attn[kk] = acc;
        lmax = fmaxf(lmax, acc);
    }
    red[t] = lmax;
    __syncthreads();
    for (int s = 128; s; s >>= 1) {
        if (t < s) red[t] = fmaxf(red[t], red[t + s]);
        __syncthreads();
    }
    const float mx = red[0];
    __syncthreads();

    // exp + sum
    float lsum = 0.0f;
    for (int kk = t; kk < L_; kk += 256) {
        const float e = expf(attn[kk] - mx);
        attn[kk] = e;
        lsum += e;
    }
    red[t] = lsum;
    __syncthreads();
    for (int s = 128; s; s >>= 1) {
        if (t < s) red[t] += red[t + s];
        __syncthreads();
    }
    const float inv = 1.0f / red[0];
    __syncthreads();

    // PV: thread t handles d = t&127, half = t>>7 of the key range
    const int d    = t & (D_ - 1);
    const int half = t >> 7;
    float acc = 0.0f;
    const int k0 = half * (L_ / 2);
    for (int kk = k0; kk < k0 + L_ / 2; ++kk)
        acc += attn[kk] * V[(((size_t)(b * L_ + kk)) * H_ + h) * D_ + d];
    red[t] = acc;
    __syncthreads();
    if (t < D_)
        out[(((size_t)(b * L_ + qi)) * H_ + h) * D_ + t] = (red[t] + red[t + 128]) * inv;
}

extern "C" void kernel_launch(void* const* d_in, const int* in_sizes, int n_in,
                              void* d_out, int out_size, void* d_ws, size_t ws_size,
                              hipStream_t stream) {
    const float* Q  = (const float*)d_in[0];
    const float* K  = (const float*)d_in[1];
    const float* V  = (const float*)d_in[2];
    const int* idx  = (const int*)d_in[3];
    float* out      = (float*)d_out;

    char* ws = (char*)d_ws;
    float* Mws   = (float*)ws;                                  // 65536 floats
    int*   topk  = (int*)(ws + 65536 * sizeof(float));          // 1280 ints
    float* vmean = (float*)(ws + 65536 * sizeof(float) + 2048 * sizeof(int)); // 4096 floats

    // A: sampled M  (65536 rows, 4 waves/block)
    hipLaunchKernelGGL(k_sampleM, dim3(16384), dim3(256), 0, stream, Q, K, idx, Mws);
    // B: top-40 per (b,h)
    hipLaunchKernelGGL(k_topk, dim3(B_ * H_), dim3(256), 0, stream, Mws, topk);
    // C: V mean
    hipLaunchKernelGGL(k_vmean, dim3(B_ * H_), dim3(256), 0, stream, V, vmean);
    // D: broadcast fill
    hipLaunchKernelGGL(k_fill, dim3(2048), dim3(256), 0, stream,
                       (float4*)out, (const float4*)vmean);
    // E: attention on selected rows (after D so it overwrites)
    hipLaunchKernelGGL(k_attn, dim3(B_ * H_ * NTOP_), dim3(256), 0, stream,
                       Q, K, V, topk, out);
}

// Round 2
// 274.067 us; speedup vs baseline: 4.1482x; 4.1482x over previous
//
#include <hip/hip_runtime.h>
#include <math.h>

#define B_    2
#define L_    2048
#define H_    16
#define D_    128
#define S_    40
#define NTOP_ 40
#define NCH_  8        // key chunks for attention / L chunks for vmean
#define CHK_  256      // keys per chunk

#define SCALE_ 0.08838834764831843f  // 1/sqrt(128)

// ---------------- A: sampled sparsity measure M[r], r = (b*H+h)*L + q --------
// One wave handles 2 consecutive q-rows (same b,h). Half-wave (32 lanes) per
// row, lane = float4 of D. 8 samples batched -> independent 5-level butterflies.
__global__ __launch_bounds__(256) void k_sampleM(const float* __restrict__ Q,
                                                 const float* __restrict__ K,
                                                 const int* __restrict__ idx,
                                                 float* __restrict__ M) {
    const int wave = threadIdx.x >> 6;
    const int lane = threadIdx.x & 63;
    const int l32  = lane & 31;
    const int half = lane >> 5;
    const int gid2 = blockIdx.x * 4 + wave;   // 0..32767, covers 2 rows each
    const int r    = gid2 * 2 + half;         // global row id 0..65535
    const int q    = r & (L_ - 1);
    const int bh   = r >> 11;
    const int h    = bh & (H_ - 1);
    const int b    = bh >> 4;

    const float4* Q4 = (const float4*)Q;
    const float4* K4 = (const float4*)K;
    const float4 qv = Q4[((size_t)(b * L_ + q) * H_ + h) * 32 + l32];
    const int* ip = idx + q * S_;

    float maxv = -INFINITY, sumv = 0.0f;
    for (int b5 = 0; b5 < 5; ++b5) {
        float p[8];
        #pragma unroll
        for (int s8 = 0; s8 < 8; ++s8) {
            const int ki = ip[b5 * 8 + s8];
            const float4 kv = K4[((size_t)(b * L_ + ki) * H_ + h) * 32 + l32];
            p[s8] = qv.x * kv.x + qv.y * kv.y + qv.z * kv.z + qv.w * kv.w;
        }
        #pragma unroll
        for (int o = 1; o < 32; o <<= 1) {
            #pragma unroll
            for (int s8 = 0; s8 < 8; ++s8) p[s8] += __shfl_xor(p[s8], o, 64);
        }
        #pragma unroll
        for (int s8 = 0; s8 < 8; ++s8) { maxv = fmaxf(maxv, p[s8]); sumv += p[s8]; }
    }
    if (l32 == 0) M[r] = maxv - sumv * (1.0f / L_);
}

// ---------------- C1: V partial sums (256 blocks) + zero topk counters -------
__global__ __launch_bounds__(256) void k_vpartial(const float* __restrict__ V,
                                                  float* __restrict__ vpart,
                                                  int* __restrict__ cnt) {
    __shared__ float red[256];
    const int bid = blockIdx.x;          // bh*8 + lc
    const int bh  = bid >> 3;
    const int lc  = bid & 7;
    const int h   = bh & (H_ - 1);
    const int b   = bh >> 4;
    const int t   = threadIdx.x;
    const int d   = t & (D_ - 1);
    const int sub = t >> 7;
    if (bid == 0 && t < 32) cnt[t] = 0;
    float acc = 0.0f;
    const int l0 = lc * 256;
    for (int l = l0 + sub; l < l0 + 256; l += 2)
        acc += V[((size_t)(b * L_ + l) * H_ + h) * D_ + d];
    red[t] = acc;
    __syncthreads();
    if (t < D_) vpart[(size_t)bid * D_ + t] = red[t] + red[t + 128];
}

// ---------------- B: rank-based top-40 selection per (b,h) -------------------
// rank(e) = #{j: M[j]>M[e]} + #{j<e: M[j]==M[e]}; selected iff rank < 40.
// Exactly matches jax.lax.top_k's selected SET (ties -> lowest index).
__global__ __launch_bounds__(256) void k_rank(const float* __restrict__ M,
                                              int* __restrict__ cnt,
                                              int* __restrict__ topk) {
    __shared__ float ml[L_];
    const int bh    = blockIdx.x >> 3;
    const int chunk = blockIdx.x & 7;
    const int t     = threadIdx.x;
    const float* Mrow = M + (size_t)bh * L_;
    for (int i = t; i < L_; i += 256) ml[i] = Mrow[i];
    __syncthreads();
    const int e = chunk * 256 + t;
    const float me = ml[e];
    const float4* m4 = (const float4*)ml;
    int gt = 0, eqb = 0;
    for (int j4 = 0; j4 < L_ / 4; ++j4) {
        const float4 v = m4[j4];
        const int j = j4 * 4;
        gt  += (v.x > me) + (v.y > me) + (v.z > me) + (v.w > me);
        eqb += ((v.x == me) & (j < e)) + ((v.y == me) & ((j + 1) < e)) +
               ((v.z == me) & ((j + 2) < e)) + ((v.w == me) & ((j + 3) < e));
    }
    if (gt + eqb < NTOP_) {
        const int pos = atomicAdd(&cnt[bh], 1);
        topk[bh * NTOP_ + pos] = e;
    }
}

// ---------------- C2: combine V partials -> mean -----------------------------
__global__ __launch_bounds__(128) void k_vcomb(const float* __restrict__ vpart,
                                               float* __restrict__ vmean) {
    const int bh = blockIdx.x;
    const int t  = threadIdx.x;
    float s = 0.0f;
    #pragma unroll
    for (int c = 0; c < NCH_; ++c) s += vpart[(size_t)(bh * NCH_ + c) * D_ + t];
    vmean[bh * D_ + t] = s * (1.0f / L_);
}

// ---------------- D: broadcast-fill output with V mean -----------------------
__global__ __launch_bounds__(256) void k_fill(float4* __restrict__ out,
                                              const float4* __restrict__ vmean4) {
    const size_t total = (size_t)B_ * L_ * H_ * D_ / 4;
    for (size_t i = blockIdx.x * 256 + threadIdx.x; i < total; i += (size_t)gridDim.x * 256) {
        const size_t flat = i * 4;
        const int d = (int)(flat & (D_ - 1));
        const int h = (int)((flat >> 7) & (H_ - 1));
        const int b = (int)(flat >> 22);
        out[i] = vmean4[(b * H_ + h) * 32 + (d >> 2)];
    }
}

// ---------------- E: chunked scores + partial softmax + partial PV -----------
// Block = (bh, kc). Thread owns key k = kc*256+t for scores (40 reg accs);
// PV: thread = (d, ugroup of 20). Partials (pre-rescale) go to workspace.
__global__ __launch_bounds__(256) void k_scorepv(const float* __restrict__ Q,
                                                 const float* __restrict__ K,
                                                 const float* __restrict__ V,
                                                 const int* __restrict__ topk,
                                                 float* __restrict__ pmax,
                                                 float* __restrict__ psum,
                                                 float* __restrict__ pout) {
    __shared__ float Qs[NTOP_ * D_];        // 20 KB
    __shared__ float S[NTOP_ * 260];        // 40.6 KB (260 stride: 16B-aligned rows)
    __shared__ float mrow[NTOP_];
    __shared__ int   tq[NTOP_];
    const int bid = blockIdx.x;             // bh*8 + kc
    const int bh  = bid >> 3;
    const int kc  = bid & 7;
    const int h   = bh & (H_ - 1);
    const int b   = bh >> 4;
    const int t   = threadIdx.x;

    if (t < NTOP_) tq[t] = topk[bh * NTOP_ + t];
    __syncthreads();

    // stage Q rows of the selected queries
    {
        const float4* Q4 = (const float4*)Q;
        float4* Qs4 = (float4*)Qs;
        #pragma unroll
        for (int it = 0; it < 5; ++it) {
            const int i = it * 256 + t;     // 0..1279
            const int u = i >> 5, dc = i & 31;
            Qs4[i] = Q4[((size_t)(b * L_ + tq[u]) * H_ + h) * 32 + dc];
        }
    }
    __syncthreads();

    // scores: key k = kc*256 + t
    {
        float acc[NTOP_];
        #pragma unroll
        for (int u = 0; u < NTOP_; ++u) acc[u] = 0.0f;
        const float4* Kb = (const float4*)K + ((size_t)(b * L_ + kc * CHK_ + t) * H_ + h) * 32;
        const float4* Qs4 = (const float4*)Qs;
        for (int dc = 0; dc < 32; ++dc) {
            const float4 kv = Kb[dc];
            #pragma unroll
            for (int u = 0; u < NTOP_; ++u) {
                const float4 qv = Qs4[u * 32 + dc];
                acc[u] += qv.x * kv.x + qv.y * kv.y + qv.z * kv.z + qv.w * kv.w;
            }
        }
        #pragma unroll
        for (int u = 0; u < NTOP_; ++u) S[u * 260 + t] = acc[u] * SCALE_;
    }
    __syncthreads();

    // per-u max over this chunk (wave w handles u = w*10 .. +10)
    {
        const int w = t >> 6, lane = t & 63;
        for (int uu = 0; uu < 10; ++uu) {
            const int u = w * 10 + uu;
            const float* Sr = S + u * 260;
            float v = fmaxf(fmaxf(Sr[lane], Sr[lane + 64]),
                            fmaxf(Sr[lane + 128], Sr[lane + 192]));
            #pragma unroll
            for (int o = 1; o < 64; o <<= 1) v = fmaxf(v, __shfl_xor(v, o, 64));
            if (lane == 0) mrow[u] = v;
        }
    }
    __syncthreads();

    // exponentiate in place
    #pragma unroll
    for (int u = 0; u < NTOP_; ++u) S[u * 260 + t] = __expf(S[u * 260 + t] - mrow[u]);
    __syncthreads();

    // per-u sum -> psum; pmax written alongside
    {
        const int w = t >> 6, lane = t & 63;
        for (int uu = 0; uu < 10; ++uu) {
            const int u = w * 10 + uu;
            const float* Sr = S + u * 260;
            float v = Sr[lane] + Sr[lane + 64] + Sr[lane + 128] + Sr[lane + 192];
            #pragma unroll
            for (int o = 1; o < 64; o <<= 1) v += __shfl_xor(v, o, 64);
            if (lane == 0) { psum[bid * NTOP_ + u] = v; pmax[bid * NTOP_ + u] = mrow[u]; }
        }
    }

    // partial PV: thread = (d, ugroup); acc over this chunk's 256 keys
    {
        const int d = t & (D_ - 1);
        const int u0 = (t >> 7) * 20;
        float acc2[20];
        #pragma unroll
        for (int u = 0; u < 20; ++u) acc2[u] = 0.0f;
        const float* Vb = V + ((size_t)(b * L_ + kc * CHK_) * H_ + h) * D_ + d;
        for (int kq = 0; kq < CHK_ / 4; ++kq) {
            const float v0 = Vb[(size_t)(kq * 4 + 0) * (H_ * D_)];
            const float v1 = Vb[(size_t)(kq * 4 + 1) * (H_ * D_)];
            const float v2 = Vb[(size_t)(kq * 4 + 2) * (H_ * D_)];
            const float v3 = Vb[(size_t)(kq * 4 + 3) * (H_ * D_)];
            #pragma unroll
            for (int u = 0; u < 20; ++u) {
                const float4 p = *(const float4*)&S[(u0 + u) * 260 + kq * 4];
                acc2[u] += p.x * v0 + p.y * v1 + p.z * v2 + p.w * v3;
            }
        }
        float* pb = pout + ((size_t)bid * NTOP_ + u0) * D_ + d;
        #pragma unroll
        for (int u = 0; u < 20; ++u) pb[(size_t)u * D_] = acc2[u];
    }
}

// ---------------- F: combine chunk partials, scatter to out ------------------
__global__ __launch_bounds__(128) void k_comb(const float* __restrict__ pmax,
                                              const float* __restrict__ psum,
                                              const float* __restrict__ pout,
                                              const int* __restrict__ topk,
                                              float* __restrict__ out) {
    const int bid = blockIdx.x;          // bh*40 + u
    const int bh  = bid / NTOP_;
    const int u   = bid - bh * NTOP_;
    const int h   = bh & (H_ - 1);
    const int b   = bh >> 4;
    const int t   = threadIdx.x;         // d

    float pm[NCH_];
    float M = -INFINITY;
    #pragma unroll
    for (int c = 0; c < NCH_; ++c) {
        pm[c] = pmax[(bh * NCH_ + c) * NTOP_ + u];
        M = fmaxf(M, pm[c]);
    }
    float ssum = 0.0f, o = 0.0f;
    #pragma unroll
    for (int c = 0; c < NCH_; ++c) {
        const float w = __expf(pm[c] - M);
        ssum += psum[(bh * NCH_ + c) * NTOP_ + u] * w;
        o += pout[((size_t)(bh * NCH_ + c) * NTOP_ + u) * D_ + t] * w;
    }
    const int qi = topk[bh * NTOP_ + u];
    out[((size_t)(b * L_ + qi) * H_ + h) * D_ + t] = o / ssum;
}

extern "C" void kernel_launch(void* const* d_in, const int* in_sizes, int n_in,
                              void* d_out, int out_size, void* d_ws, size_t ws_size,
                              hipStream_t stream) {
    const float* Q  = (const float*)d_in[0];
    const float* K  = (const float*)d_in[1];
    const float* V  = (const float*)d_in[2];
    const int* idx  = (const int*)d_in[3];
    float* out      = (float*)d_out;

    char* ws = (char*)d_ws;
    size_t off = 0;
    float* Mws   = (float*)(ws + off); off += (size_t)65536 * 4;
    float* vpart = (float*)(ws + off); off += (size_t)256 * 128 * 4;
    float* vmean = (float*)(ws + off); off += (size_t)4096 * 4;
    int*   cnt   = (int*)(ws + off);   off += 32 * 4;
    int*   topk  = (int*)(ws + off);   off += 1280 * 4;
    float* pmax  = (float*)(ws + off); off += (size_t)256 * 40 * 4;
    float* psum  = (float*)(ws + off); off += (size_t)256 * 40 * 4;
    float* pout  = (float*)(ws + off); off += (size_t)256 * 40 * 128 * 4;

    hipLaunchKernelGGL(k_sampleM,  dim3(8192), dim3(256), 0, stream, Q, K, idx, Mws);
    hipLaunchKernelGGL(k_vpartial, dim3(256),  dim3(256), 0, stream, V, vpart, cnt);
    hipLaunchKernelGGL(k_rank,     dim3(256),  dim3(256), 0, stream, Mws, cnt, topk);
    hipLaunchKernelGGL(k_vcomb,    dim3(32),   dim3(128), 0, stream, vpart, vmean);
    hipLaunchKernelGGL(k_fill,     dim3(2048), dim3(256), 0, stream,
                       (float4*)out, (const float4*)vmean);
    hipLaunchKernelGGL(k_scorepv,  dim3(256),  dim3(256), 0, stream,
                       Q, K, V, topk, pmax, psum, pout);
    hipLaunchKernelGGL(k_comb,     dim3(1280), dim3(128), 0, stream,
                       pmax, psum, pout, topk, out);
}

// Round 3
// 218.774 us; speedup vs baseline: 5.1966x; 1.2527x over previous
//
#include <hip/hip_runtime.h>
#include <math.h>

#define B_    2
#define L_    2048
#define H_    16
#define D_    128
#define S_    40
#define NTOP_ 40
#define NCH_  8        // key chunks for attention
#define CHK_  256      // keys per chunk
#define VCH_  32       // L chunks for vmean

#define SCALE_ 0.08838834764831843f  // 1/sqrt(128)

// ---------------- A: sampled sparsity measure M[r], r = (b*H+h)*L + q --------
// XCD-aware: xcd = blockIdx&7 owns bh in [xcd*4, xcd*4+4), walking q within a
// bh slice so the 1 MB K slice stays resident in that XCD's L2.
// One wave handles 2 q-rows (same bh). Half-wave per row, lane = float4 of D.
__global__ __launch_bounds__(256) void k_sampleM(const float* __restrict__ Q,
                                                 const float* __restrict__ K,
                                                 const int* __restrict__ idx,
                                                 float* __restrict__ M) {
    const int xcd  = blockIdx.x & 7;
    const int li   = blockIdx.x >> 3;         // 0..1023
    const int bh   = xcd * 4 + (li >> 8);     // 4 bh per XCD
    const int qb   = li & 255;                // 256 q-blocks per bh
    const int wave = threadIdx.x >> 6;
    const int lane = threadIdx.x & 63;
    const int l32  = lane & 31;
    const int half = lane >> 5;
    const int q    = qb * 8 + wave * 2 + half;
    const int r    = bh * L_ + q;
    const int h    = bh & (H_ - 1);
    const int b    = bh >> 4;

    const float4* Q4 = (const float4*)Q;
    const float4* K4 = (const float4*)K;
    const float4 qv = Q4[((size_t)(b * L_ + q) * H_ + h) * 32 + l32];
    const int* ip = idx + q * S_;

    float maxv = -INFINITY, sumv = 0.0f;
    for (int b5 = 0; b5 < 5; ++b5) {
        float p[8];
        #pragma unroll
        for (int s8 = 0; s8 < 8; ++s8) {
            const int ki = ip[b5 * 8 + s8];
            const float4 kv = K4[((size_t)(b * L_ + ki) * H_ + h) * 32 + l32];
            p[s8] = qv.x * kv.x + qv.y * kv.y + qv.z * kv.z + qv.w * kv.w;
        }
        #pragma unroll
        for (int o = 1; o < 32; o <<= 1) {
            #pragma unroll
            for (int s8 = 0; s8 < 8; ++s8) p[s8] += __shfl_xor(p[s8], o, 64);
        }
        #pragma unroll
        for (int s8 = 0; s8 < 8; ++s8) { maxv = fmaxf(maxv, p[s8]); sumv += p[s8]; }
    }
    if (l32 == 0) M[r] = maxv - sumv * (1.0f / L_);
}

// ---------------- C1: V partial sums (1024 blocks) + zero topk counters ------
__global__ __launch_bounds__(256) void k_vpartial(const float* __restrict__ V,
                                                  float* __restrict__ vpart,
                                                  int* __restrict__ cnt) {
    __shared__ float red[256];
    const int bid = blockIdx.x;          // bh*VCH_ + lc
    const int bh  = bid >> 5;
    const int lc  = bid & (VCH_ - 1);
    const int h   = bh & (H_ - 1);
    const int b   = bh >> 4;
    const int t   = threadIdx.x;
    const int d   = t & (D_ - 1);
    const int sub = t >> 7;
    if (bid == 0 && t < 32) cnt[t] = 0;
    float acc = 0.0f;
    const int l0 = lc * (L_ / VCH_);     // 64 rows per chunk
    for (int l = l0 + sub; l < l0 + L_ / VCH_; l += 2)
        acc += V[((size_t)(b * L_ + l) * H_ + h) * D_ + d];
    red[t] = acc;
    __syncthreads();
    if (t < D_) vpart[(size_t)bid * D_ + t] = red[t] + red[t + 128];
}

// ---------------- B: rank-based top-40 selection per (b,h) -------------------
// rank(e) = #{j: M[j]>M[e]} + #{j<e: M[j]==M[e]}; selected iff rank < 40.
// Exactly matches jax.lax.top_k's selected SET (ties -> lowest index).
__global__ __launch_bounds__(256) void k_rank(const float* __restrict__ M,
                                              int* __restrict__ cnt,
                                              int* __restrict__ topk) {
    __shared__ float ml[L_];
    const int bh    = blockIdx.x >> 3;
    const int chunk = blockIdx.x & 7;
    const int t     = threadIdx.x;
    const float* Mrow = M + (size_t)bh * L_;
    for (int i = t; i < L_; i += 256) ml[i] = Mrow[i];
    __syncthreads();
    const int e = chunk * 256 + t;
    const float me = ml[e];
    const float4* m4 = (const float4*)ml;
    int gt = 0, eqb = 0;
    for (int j4 = 0; j4 < L_ / 4; ++j4) {
        const float4 v = m4[j4];
        const int j = j4 * 4;
        gt  += (v.x > me) + (v.y > me) + (v.z > me) + (v.w > me);
        eqb += ((v.x == me) & (j < e)) + ((v.y == me) & ((j + 1) < e)) +
               ((v.z == me) & ((j + 2) < e)) + ((v.w == me) & ((j + 3) < e));
    }
    if (gt + eqb < NTOP_) {
        const int pos = atomicAdd(&cnt[bh], 1);
        topk[bh * NTOP_ + pos] = e;
    }
}

// ---------------- C2: combine V partials -> mean -----------------------------
__global__ __launch_bounds__(128) void k_vcomb(const float* __restrict__ vpart,
                                               float* __restrict__ vmean) {
    const int bh = blockIdx.x;
    const int t  = threadIdx.x;
    float s = 0.0f;
    #pragma unroll
    for (int c = 0; c < VCH_; ++c) s += vpart[(size_t)(bh * VCH_ + c) * D_ + t];
    vmean[bh * D_ + t] = s * (1.0f / L_);
}

// ---------------- D: broadcast-fill output with V mean -----------------------
__global__ __launch_bounds__(256) void k_fill(float4* __restrict__ out,
                                              const float4* __restrict__ vmean4) {
    const size_t total = (size_t)B_ * L_ * H_ * D_ / 4;
    for (size_t i = blockIdx.x * 256 + threadIdx.x; i < total; i += (size_t)gridDim.x * 256) {
        const size_t flat = i * 4;
        const int d = (int)(flat & (D_ - 1));
        const int h = (int)((flat >> 7) & (H_ - 1));
        const int b = (int)(flat >> 22);
        out[i] = vmean4[(b * H_ + h) * 32 + (d >> 2)];
    }
}

// ---------------- E: chunked scores + partial softmax + partial PV -----------
// Block = (bh, kc, uh): uh = half of the 40 selected queries (20 each).
// Thread owns key k = kc*256+t for scores (20 reg accs);
// PV: thread = (d, ugroup of 10). Partials (pre-rescale) go to workspace.
__global__ __launch_bounds__(256) void k_scorepv(const float* __restrict__ Q,
                                                 const float* __restrict__ K,
                                                 const float* __restrict__ V,
                                                 const int* __restrict__ topk,
                                                 float* __restrict__ pmax,
                                                 float* __restrict__ psum,
                                                 float* __restrict__ pout) {
    __shared__ float Qs[20 * D_];           // 10 KB
    __shared__ float S[20 * 260];           // 20.3 KB (260 stride: aligned rows)
    __shared__ float mrow[20];
    __shared__ int   tq[20];
    const int bid = blockIdx.x;             // (bh*8 + kc)*2 + uh
    const int uh  = bid & 1;
    const int kc  = (bid >> 1) & 7;
    const int bh  = bid >> 4;
    const int h   = bh & (H_ - 1);
    const int b   = bh >> 4;
    const int t   = threadIdx.x;

    if (t < 20) tq[t] = topk[bh * NTOP_ + uh * 20 + t];
    __syncthreads();

    // stage the 20 selected Q rows (640 float4)
    {
        const float4* Q4 = (const float4*)Q;
        float4* Qs4 = (float4*)Qs;
        #pragma unroll
        for (int it = 0; it < 3; ++it) {
            const int i = it * 256 + t;
            if (i < 640) {
                const int u = i >> 5, dc = i & 31;
                Qs4[i] = Q4[((size_t)(b * L_ + tq[u]) * H_ + h) * 32 + dc];
            }
        }
    }
    __syncthreads();

    // scores: key k = kc*256 + t
    {
        float acc[20];
        #pragma unroll
        for (int u = 0; u < 20; ++u) acc[u] = 0.0f;
        const float4* Kb = (const float4*)K + ((size_t)(b * L_ + kc * CHK_ + t) * H_ + h) * 32;
        const float4* Qs4 = (const float4*)Qs;
        for (int dc = 0; dc < 32; ++dc) {
            const float4 kv = Kb[dc];
            #pragma unroll
            for (int u = 0; u < 20; ++u) {
                const float4 qv = Qs4[u * 32 + dc];
                acc[u] += qv.x * kv.x + qv.y * kv.y + qv.z * kv.z + qv.w * kv.w;
            }
        }
        #pragma unroll
        for (int u = 0; u < 20; ++u) S[u * 260 + t] = acc[u] * SCALE_;
    }
    __syncthreads();

    // per-u max over this chunk (wave w handles 5 u's)
    {
        const int w = t >> 6, lane = t & 63;
        #pragma unroll
        for (int uu = 0; uu < 5; ++uu) {
            const int u = w * 5 + uu;
            const float* Sr = S + u * 260;
            float v = fmaxf(fmaxf(Sr[lane], Sr[lane + 64]),
                            fmaxf(Sr[lane + 128], Sr[lane + 192]));
            #pragma unroll
            for (int o = 1; o < 64; o <<= 1) v = fmaxf(v, __shfl_xor(v, o, 64));
            if (lane == 0) mrow[u] = v;
        }
    }
    __syncthreads();

    // exponentiate in place
    #pragma unroll
    for (int u = 0; u < 20; ++u) S[u * 260 + t] = __expf(S[u * 260 + t] - mrow[u]);
    __syncthreads();

    // per-u sum -> psum; pmax alongside
    {
        const int w = t >> 6, lane = t & 63;
        #pragma unroll
        for (int uu = 0; uu < 5; ++uu) {
            const int u = w * 5 + uu;
            const float* Sr = S + u * 260;
            float v = Sr[lane] + Sr[lane + 64] + Sr[lane + 128] + Sr[lane + 192];
            #pragma unroll
            for (int o = 1; o < 64; o <<= 1) v += __shfl_xor(v, o, 64);
            if (lane == 0) {
                psum[(bh * NCH_ + kc) * NTOP_ + uh * 20 + u] = v;
                pmax[(bh * NCH_ + kc) * NTOP_ + uh * 20 + u] = mrow[u];
            }
        }
    }

    // partial PV: thread = (d, ugroup of 10); acc over this chunk's 256 keys
    {
        const int d  = t & (D_ - 1);
        const int g  = t >> 7;               // 0 or 1
        const int u0 = g * 10;
        float acc2[10];
        #pragma unroll
        for (int u = 0; u < 10; ++u) acc2[u] = 0.0f;
        const float* Vb = V + ((size_t)(b * L_ + kc * CHK_) * H_ + h) * D_ + d;
        for (int kq = 0; kq < CHK_ / 4; ++kq) {
            const float v0 = Vb[(size_t)(kq * 4 + 0) * (H_ * D_)];
            const float v1 = Vb[(size_t)(kq * 4 + 1) * (H_ * D_)];
            const float v2 = Vb[(size_t)(kq * 4 + 2) * (H_ * D_)];
            const float v3 = Vb[(size_t)(kq * 4 + 3) * (H_ * D_)];
            #pragma unroll
            for (int u = 0; u < 10; ++u) {
                const float4 p = *(const float4*)&S[(u0 + u) * 260 + kq * 4];
                acc2[u] += p.x * v0 + p.y * v1 + p.z * v2 + p.w * v3;
            }
        }
        float* pb = pout + (((size_t)(bh * NCH_ + kc)) * NTOP_ + uh * 20 + u0) * D_ + d;
        #pragma unroll
        for (int u = 0; u < 10; ++u) pb[(size_t)u * D_] = acc2[u];
    }
}

// ---------------- F: combine chunk partials, scatter to out ------------------
__global__ __launch_bounds__(128) void k_comb(const float* __restrict__ pmax,
                                              const float* __restrict__ psum,
                                              const float* __restrict__ pout,
                                              const int* __restrict__ topk,
                                              float* __restrict__ out) {
    const int bid = blockIdx.x;          // bh*40 + u
    const int bh  = bid / NTOP_;
    const int u   = bid - bh * NTOP_;
    const int h   = bh & (H_ - 1);
    const int b   = bh >> 4;
    const int t   = threadIdx.x;         // d

    float pm[NCH_];
    float M = -INFINITY;
    #pragma unroll
    for (int c = 0; c < NCH_; ++c) {
        pm[c] = pmax[(bh * NCH_ + c) * NTOP_ + u];
        M = fmaxf(M, pm[c]);
    }
    float ssum = 0.0f, o = 0.0f;
    #pragma unroll
    for (int c = 0; c < NCH_; ++c) {
        const float w = __expf(pm[c] - M);
        ssum += psum[(bh * NCH_ + c) * NTOP_ + u] * w;
        o += pout[((size_t)(bh * NCH_ + c) * NTOP_ + u) * D_ + t] * w;
    }
    const int qi = topk[bh * NTOP_ + u];
    out[((size_t)(b * L_ + qi) * H_ + h) * D_ + t] = o / ssum;
}

extern "C" void kernel_launch(void* const* d_in, const int* in_sizes, int n_in,
                              void* d_out, int out_size, void* d_ws, size_t ws_size,
                              hipStream_t stream) {
    const float* Q  = (const float*)d_in[0];
    const float* K  = (const float*)d_in[1];
    const float* V  = (const float*)d_in[2];
    const int* idx  = (const int*)d_in[3];
    float* out      = (float*)d_out;

    char* ws = (char*)d_ws;
    size_t off = 0;
    float* Mws   = (float*)(ws + off); off += (size_t)65536 * 4;
    float* vpart = (float*)(ws + off); off += (size_t)1024 * 128 * 4;
    float* vmean = (float*)(ws + off); off += (size_t)4096 * 4;
    int*   cnt   = (int*)(ws + off);   off += 32 * 4;
    int*   topk  = (int*)(ws + off);   off += 1280 * 4;
    float* pmax  = (float*)(ws + off); off += (size_t)256 * 40 * 4;
    float* psum  = (float*)(ws + off); off += (size_t)256 * 40 * 4;
    float* pout  = (float*)(ws + off); off += (size_t)256 * 40 * 128 * 4;

    hipLaunchKernelGGL(k_sampleM,  dim3(8192), dim3(256), 0, stream, Q, K, idx, Mws);
    hipLaunchKernelGGL(k_vpartial, dim3(1024), dim3(256), 0, stream, V, vpart, cnt);
    hipLaunchKernelGGL(k_rank,     dim3(256),  dim3(256), 0, stream, Mws, cnt, topk);
    hipLaunchKernelGGL(k_vcomb,    dim3(32),   dim3(128), 0, stream, vpart, vmean);
    hipLaunchKernelGGL(k_fill,     dim3(2048), dim3(256), 0, stream,
                       (float4*)out, (const float4*)vmean);
    hipLaunchKernelGGL(k_scorepv,  dim3(512),  dim3(256), 0, stream,
                       Q, K, V, topk, pmax, psum, pout);
    hipLaunchKernelGGL(k_comb,     dim3(1280), dim3(128), 0, stream,
                       pmax, psum, pout, topk, out);
}

// Round 4
// 192.264 us; speedup vs baseline: 5.9131x; 1.1379x over previous
//
#include <hip/hip_runtime.h>
#include <math.h>

#define B_    2
#define L_    2048
#define H_    16
#define D_    128
#define S_    40
#define NTOP_ 40
#define NCH_  8        // key chunks for attention
#define CHK_  256      // keys per chunk
#define VCH_  32       // L chunks for vmean

#define SCALE_ 0.08838834764831843f  // 1/sqrt(128)

#define NSAMP_BLKS 16384   // sampleM: 4 rows per block (1 per wave)
#define NVP_BLKS   1024    // vpartial blocks

// ---------------- K1: fused sampleM (+vpartial, +cnt zero) -------------------
// sampleM: one wave per q-row. 8 lanes span D=128 (16 floats/lane), so each
// 64-lane instruction covers 8 samples. Dot reduce = 3-level xor (1,2,4);
// cross-group max/sum = 3 more xors (8,16,32). 21 shuffles/row vs 100 before.
// XCD-aware: xcd = bid&7 owns bh in [xcd*4, xcd*4+4) so the 1 MB K slice
// stays resident in that XCD's L2.
__global__ __launch_bounds__(256) void k1_sample_vpart(const float* __restrict__ Q,
                                                       const float* __restrict__ K,
                                                       const float* __restrict__ V,
                                                       const int* __restrict__ idx,
                                                       float* __restrict__ M,
                                                       float* __restrict__ vpart,
                                                       int* __restrict__ cnt) {
    const int bid = blockIdx.x;
    const int t   = threadIdx.x;

    if (bid < NSAMP_BLKS) {
        if (bid == 0 && t < 32) cnt[t] = 0;
        const int xcd  = bid & 7;
        const int li   = bid >> 3;                // 0..2047
        const int bh   = (xcd << 2) + (li >> 9);  // 4 bh per XCD
        const int rb   = li & 511;                // 512 row-blocks per bh
        const int wave = t >> 6;
        const int lane = t & 63;
        const int q    = rb * 4 + wave;
        const int h    = bh & (H_ - 1);
        const int b    = bh >> 4;
        const int group = lane >> 3;              // 0..7 : sample within slot
        const int sub   = lane & 7;               // float4 within D

        const float4* Q4 = (const float4*)Q;
        const float4* K4 = (const float4*)K;
        const size_t rowQ = ((size_t)(b * L_ + q) * H_ + h) * 32;
        const float4 qv0 = Q4[rowQ + 0  + sub];
        const float4 qv1 = Q4[rowQ + 8  + sub];
        const float4 qv2 = Q4[rowQ + 16 + sub];
        const float4 qv3 = Q4[rowQ + 24 + sub];
        const size_t kbase = ((size_t)b * L_ * H_ + h) * 32 + sub;  // + ki*(H_*32)
        const int* ip = idx + q * S_;

        float smax = -INFINITY, ssum = 0.0f;
        #pragma unroll
        for (int slot = 0; slot < 5; ++slot) {
            const int ki = ip[slot * 8 + group];
            const float4* kb = K4 + kbase + (size_t)ki * (H_ * 32);
            float4 kv = kb[0];
            float p  = qv0.x * kv.x + qv0.y * kv.y + qv0.z * kv.z + qv0.w * kv.w;
            kv = kb[8];
            p += qv1.x * kv.x + qv1.y * kv.y + qv1.z * kv.z + qv1.w * kv.w;
            kv = kb[16];
            p += qv2.x * kv.x + qv2.y * kv.y + qv2.z * kv.z + qv2.w * kv.w;
            kv = kb[24];
            p += qv3.x * kv.x + qv3.y * kv.y + qv3.z * kv.z + qv3.w * kv.w;
            // 3-level reduce within the 8-lane group -> full dot on every lane
            p += __shfl_xor(p, 1);
            p += __shfl_xor(p, 2);
            p += __shfl_xor(p, 4);
            smax = fmaxf(smax, p);
            ssum += p;
        }
        // cross-group combine (values identical within each 8-lane group)
        #pragma unroll
        for (int o = 8; o < 64; o <<= 1) {
            smax = fmaxf(smax, __shfl_xor(smax, o));
            ssum += __shfl_xor(ssum, o);
        }
        if (lane == 0) M[bh * L_ + q] = smax - ssum * (1.0f / L_);
    } else {
        // ---- vpartial ----
        __shared__ float red[256];
        const int vbid = bid - NSAMP_BLKS;   // bh*VCH_ + lc
        const int bh  = vbid >> 5;
        const int lc  = vbid & (VCH_ - 1);
        const int h   = bh & (H_ - 1);
        const int b   = bh >> 4;
        const int d   = t & (D_ - 1);
        const int sub = t >> 7;
        float acc = 0.0f;
        const int l0 = lc * (L_ / VCH_);     // 64 rows per chunk
        for (int l = l0 + sub; l < l0 + L_ / VCH_; l += 2)
            acc += V[((size_t)(b * L_ + l) * H_ + h) * D_ + d];
        red[t] = acc;
        __syncthreads();
        if (t < D_) vpart[(size_t)vbid * D_ + t] = red[t] + red[t + 128];
    }
}

// ---------------- K2: fused rank (top-40) + broadcast fill -------------------
// blocks 0..255: rank-select per (b,h): rank(e) = #{j: M[j]>M[e]} +
//   #{j<e: M[j]==M[e]}; selected iff rank < 40 (matches jax.lax.top_k SET).
// blocks 256..2303: fill out[b, q0..q0+32, h, :] with vmean computed locally
//   from the L2-resident vpart.
__global__ __launch_bounds__(256) void k2_rank_fill(const float* __restrict__ M,
                                                    const float* __restrict__ vpart,
                                                    int* __restrict__ cnt,
                                                    int* __restrict__ topk,
                                                    float* __restrict__ out) {
    __shared__ float ml[L_];
    const int bid = blockIdx.x;
    const int t   = threadIdx.x;

    if (bid < 256) {
        const int bh    = bid >> 3;
        const int chunk = bid & 7;
        const float* Mrow = M + (size_t)bh * L_;
        for (int i = t; i < L_; i += 256) ml[i] = Mrow[i];
        __syncthreads();
        const int e = chunk * 256 + t;
        const float me = ml[e];
        const float4* m4 = (const float4*)ml;
        int gt = 0, eqb = 0;
        for (int j4 = 0; j4 < L_ / 4; ++j4) {
            const float4 v = m4[j4];
            const int j = j4 * 4;
            gt  += (v.x > me) + (v.y > me) + (v.z > me) + (v.w > me);
            eqb += ((v.x == me) & (j < e)) + ((v.y == me) & ((j + 1) < e)) +
                   ((v.z == me) & ((j + 2) < e)) + ((v.w == me) & ((j + 3) < e));
        }
        if (gt + eqb < NTOP_) {
            const int pos = atomicAdd(&cnt[bh], 1);
            topk[bh * NTOP_ + pos] = e;
        }
    } else {
        const int fb = bid - 256;            // 0..2047
        const int bh = fb >> 6;
        const int sl = fb & 63;              // 64 slices of 32 q-rows
        const int h  = bh & (H_ - 1);
        const int b  = bh >> 4;
        // local vmean for this bh
        const int d    = t & (D_ - 1);
        const int half = t >> 7;
        float s = 0.0f;
        #pragma unroll
        for (int c = half * 16; c < half * 16 + 16; ++c)
            s += vpart[(size_t)(bh * VCH_ + c) * D_ + d];
        ml[t] = s;
        __syncthreads();
        if (t < D_) ml[t] = (ml[t] + ml[t + 128]) * (1.0f / L_);
        __syncthreads();
        const float4 vm4 = *(const float4*)&ml[(t & 31) * 4];
        float4* out4 = (float4*)out;
        const int q0 = sl * 32;
        #pragma unroll
        for (int k = 0; k < 4; ++k) {
            const int j = k * 256 + t;
            const int r = j >> 5;            // row within slice, col = t&31
            out4[((size_t)(b * L_ + q0 + r) * H_ + h) * 32 + (t & 31)] = vm4;
        }
    }
}

// ---------------- K3: chunked scores + partial softmax + partial PV ----------
// Block = (bh, kc, uh): uh = half of the 40 selected queries (20 each).
__global__ __launch_bounds__(256) void k_scorepv(const float* __restrict__ Q,
                                                 const float* __restrict__ K,
                                                 const float* __restrict__ V,
                                                 const int* __restrict__ topk,
                                                 float* __restrict__ pmax,
                                                 float* __restrict__ psum,
                                                 float* __restrict__ pout) {
    __shared__ float Qs[20 * D_];           // 10 KB
    __shared__ float S[20 * 260];           // 20.3 KB
    __shared__ float mrow[20];
    __shared__ int   tq[20];
    const int bid = blockIdx.x;             // (bh*8 + kc)*2 + uh
    const int uh  = bid & 1;
    const int kc  = (bid >> 1) & 7;
    const int bh  = bid >> 4;
    const int h   = bh & (H_ - 1);
    const int b   = bh >> 4;
    const int t   = threadIdx.x;

    if (t < 20) tq[t] = topk[bh * NTOP_ + uh * 20 + t];
    __syncthreads();

    {
        const float4* Q4 = (const float4*)Q;
        float4* Qs4 = (float4*)Qs;
        #pragma unroll
        for (int it = 0; it < 3; ++it) {
            const int i = it * 256 + t;
            if (i < 640) {
                const int u = i >> 5, dc = i & 31;
                Qs4[i] = Q4[((size_t)(b * L_ + tq[u]) * H_ + h) * 32 + dc];
            }
        }
    }
    __syncthreads();

    {
        float acc[20];
        #pragma unroll
        for (int u = 0; u < 20; ++u) acc[u] = 0.0f;
        const float4* Kb = (const float4*)K + ((size_t)(b * L_ + kc * CHK_ + t) * H_ + h) * 32;
        const float4* Qs4 = (const float4*)Qs;
        for (int dc = 0; dc < 32; ++dc) {
            const float4 kv = Kb[dc];
            #pragma unroll
            for (int u = 0; u < 20; ++u) {
                const float4 qv = Qs4[u * 32 + dc];
                acc[u] += qv.x * kv.x + qv.y * kv.y + qv.z * kv.z + qv.w * kv.w;
            }
        }
        #pragma unroll
        for (int u = 0; u < 20; ++u) S[u * 260 + t] = acc[u] * SCALE_;
    }
    __syncthreads();

    {
        const int w = t >> 6, lane = t & 63;
        #pragma unroll
        for (int uu = 0; uu < 5; ++uu) {
            const int u = w * 5 + uu;
            const float* Sr = S + u * 260;
            float v = fmaxf(fmaxf(Sr[lane], Sr[lane + 64]),
                            fmaxf(Sr[lane + 128], Sr[lane + 192]));
            #pragma unroll
            for (int o = 1; o < 64; o <<= 1) v = fmaxf(v, __shfl_xor(v, o, 64));
            if (lane == 0) mrow[u] = v;
        }
    }
    __syncthreads();

    #pragma unroll
    for (int u = 0; u < 20; ++u) S[u * 260 + t] = __expf(S[u * 260 + t] - mrow[u]);
    __syncthreads();

    {
        const int w = t >> 6, lane = t & 63;
        #pragma unroll
        for (int uu = 0; uu < 5; ++uu) {
            const int u = w * 5 + uu;
            const float* Sr = S + u * 260;
            float v = Sr[lane] + Sr[lane + 64] + Sr[lane + 128] + Sr[lane + 192];
            #pragma unroll
            for (int o = 1; o < 64; o <<= 1) v += __shfl_xor(v, o, 64);
            if (lane == 0) {
                psum[(bh * NCH_ + kc) * NTOP_ + uh * 20 + u] = v;
                pmax[(bh * NCH_ + kc) * NTOP_ + uh * 20 + u] = mrow[u];
            }
        }
    }

    {
        const int d  = t & (D_ - 1);
        const int g  = t >> 7;
        const int u0 = g * 10;
        float acc2[10];
        #pragma unroll
        for (int u = 0; u < 10; ++u) acc2[u] = 0.0f;
        const float* Vb = V + ((size_t)(b * L_ + kc * CHK_) * H_ + h) * D_ + d;
        for (int kq = 0; kq < CHK_ / 4; ++kq) {
            const float v0 = Vb[(size_t)(kq * 4 + 0) * (H_ * D_)];
            const float v1 = Vb[(size_t)(kq * 4 + 1) * (H_ * D_)];
            const float v2 = Vb[(size_t)(kq * 4 + 2) * (H_ * D_)];
            const float v3 = Vb[(size_t)(kq * 4 + 3) * (H_ * D_)];
            #pragma unroll
            for (int u = 0; u < 10; ++u) {
                const float4 p = *(const float4*)&S[(u0 + u) * 260 + kq * 4];
                acc2[u] += p.x * v0 + p.y * v1 + p.z * v2 + p.w * v3;
            }
        }
        float* pb = pout + (((size_t)(bh * NCH_ + kc)) * NTOP_ + uh * 20 + u0) * D_ + d;
        #pragma unroll
        for (int u = 0; u < 10; ++u) pb[(size_t)u * D_] = acc2[u];
    }
}

// ---------------- K4: combine chunk partials, scatter to out -----------------
__global__ __launch_bounds__(128) void k_comb(const float* __restrict__ pmax,
                                              const float* __restrict__ psum,
                                              const float* __restrict__ pout,
                                              const int* __restrict__ topk,
                                              float* __restrict__ out) {
    const int bid = blockIdx.x;          // bh*40 + u
    const int bh  = bid / NTOP_;
    const int u   = bid - bh * NTOP_;
    const int h   = bh & (H_ - 1);
    const int b   = bh >> 4;
    const int t   = threadIdx.x;         // d

    float pm[NCH_];
    float M = -INFINITY;
    #pragma unroll
    for (int c = 0; c < NCH_; ++c) {
        pm[c] = pmax[(bh * NCH_ + c) * NTOP_ + u];
        M = fmaxf(M, pm[c]);
    }
    float ssum = 0.0f, o = 0.0f;
    #pragma unroll
    for (int c = 0; c < NCH_; ++c) {
        const float w = __expf(pm[c] - M);
        ssum += psum[(bh * NCH_ + c) * NTOP_ + u] * w;
        o += pout[((size_t)(bh * NCH_ + c) * NTOP_ + u) * D_ + t] * w;
    }
    const int qi = topk[bh * NTOP_ + u];
    out[((size_t)(b * L_ + qi) * H_ + h) * D_ + t] = o / ssum;
}

extern "C" void kernel_launch(void* const* d_in, const int* in_sizes, int n_in,
                              void* d_out, int out_size, void* d_ws, size_t ws_size,
                              hipStream_t stream) {
    const float* Q  = (const float*)d_in[0];
    const float* K  = (const float*)d_in[1];
    const float* V  = (const float*)d_in[2];
    const int* idx  = (const int*)d_in[3];
    float* out      = (float*)d_out;

    char* ws = (char*)d_ws;
    size_t off = 0;
    float* Mws   = (float*)(ws + off); off += (size_t)65536 * 4;
    float* vpart = (float*)(ws + off); off += (size_t)1024 * 128 * 4;
    int*   cnt   = (int*)(ws + off);   off += 32 * 4;
    int*   topk  = (int*)(ws + off);   off += 1280 * 4;
    float* pmax  = (float*)(ws + off); off += (size_t)256 * 40 * 4;
    float* psum  = (float*)(ws + off); off += (size_t)256 * 40 * 4;
    float* pout  = (float*)(ws + off); off += (size_t)256 * 40 * 128 * 4;

    hipLaunchKernelGGL(k1_sample_vpart, dim3(NSAMP_BLKS + NVP_BLKS), dim3(256), 0, stream,
                       Q, K, V, idx, Mws, vpart, cnt);
    hipLaunchKernelGGL(k2_rank_fill,    dim3(256 + 2048), dim3(256), 0, stream,
                       Mws, vpart, cnt, topk, out);
    hipLaunchKernelGGL(k_scorepv,       dim3(512),  dim3(256), 0, stream,
                       Q, K, V, topk, pmax, psum, pout);
    hipLaunchKernelGGL(k_comb,          dim3(1280), dim3(128), 0, stream,
                       pmax, psum, pout, topk, out);
}